// Round 12
// baseline (98.019 us; speedup 1.0000x reference)
//
#include <hip/hip_runtime.h>
#include <hip/hip_bf16.h>

// CausalAttentionPixelBlock: 24 independent causal attns (3 stacks x 8 heads),
// seq=2048, head dim ck=8, fp32 in/out, channels-first [c][pos].
// R9/R10 accounting: floor ~58.5us (harness fills), prepass ~16us, attn ~17.4us.
// R11: 64-row strips w/ 4 Q-frags per wave (4x K/V load amortization) + Q-pack
// folded into attn_main (prepass = K + V only).
constexpr int NPROB   = 24;
constexpr int SEQ     = 2048;
constexpr int CK      = 8;
constexpr int NSTRIP64 = SEQ / 64;  // 32 strips of 64 query rows per prob

typedef __attribute__((ext_vector_type(8))) short bf16x8;  // MFMA A/B frag (8 bf16)
typedef __attribute__((ext_vector_type(4))) float f32x4;   // MFMA C/D frag

// ck^-0.5 * log2(e): exp(x) -> exp2(x') with scale folded into Q
__device__ constexpr float QSCALE = 0.35355339059327373f * 1.4426950408889634f;

__device__ inline unsigned packbf(float a, float b) {
    float2 t{a, b};
    __hip_bfloat162 h = __float22bfloat162_rn(t);
    unsigned r; __builtin_memcpy(&r, &h, 4); return r;
}

// ---------------- prepass: K + V only (Q packed in attn_main) ----------------
// Kt: [prob][j][8] bf16 (K transposed)                                 786 KB
// V16:[prob][chunk][64] uint4, chunk = 32 keys. Entry (chunk p, l=g*16+row):
//     V[row][32p + {4g..4g+3, 16+4g..16+4g+3}] (sigma key order). Row 8 = 1.0
//     (free rowsum), rows 9-15 = 0.                                    1.57 MB
constexpr int TK = NPROB * SEQ;            // Kt items (one key each)     49152
constexpr int TB = NPROB * CK * (SEQ / 8); // V16 rows 0-7                49152
constexpr int TC = NPROB * 8  * (SEQ / 8); // V16 rows 8-15 fill          49152

__global__ __launch_bounds__(256) void prepass(
    const float* __restrict__ K, const float* __restrict__ V,
    uint4* __restrict__ Kt4, uint4* __restrict__ V164)
{
    const int t = blockIdx.x * 256 + threadIdx.x;
    if (t < TK) {
        const int prob = t >> 11, j = t & (SEQ - 1);
        const float* ks = K + prob * CK * SEQ + j;   // lane-consecutive j: coalesced
        uint4 ko;
        ko.x = packbf(ks[0 * SEQ], ks[1 * SEQ]);
        ko.y = packbf(ks[2 * SEQ], ks[3 * SEQ]);
        ko.z = packbf(ks[4 * SEQ], ks[5 * SEQ]);
        ko.w = packbf(ks[6 * SEQ], ks[7 * SEQ]);
        Kt4[t] = ko;                                  // dense 16B stores
    } else if (t < TK + TB) {
        const int idx  = t - TK;
        const int prob = idx >> 11;
        const int rem  = idx & 2047;
        const int c    = rem >> 8;             // V row (channel) 0..7
        const int u    = rem & 255;
        const int c32  = u >> 2;               // 32-key chunk 0..63
        const int g    = u & 3;                // k-group within chunk
        const float* vs = V + prob * CK * SEQ + c * SEQ + c32 * 32;
        const float4 a = *reinterpret_cast<const float4*>(vs + 4 * g);       // keys 4g..4g+3
        const float4 b = *reinterpret_cast<const float4*>(vs + 16 + 4 * g);  // keys 16+4g..
        uint4 vo;
        vo.x = packbf(a.x, a.y); vo.y = packbf(a.z, a.w);
        vo.z = packbf(b.x, b.y); vo.w = packbf(b.z, b.w);
        V164[prob * 4096 + c32 * 64 + g * 16 + c] = vo;   // [prob][chunk][g*16+row]
    } else {
        const int idx  = t - TK - TB;
        const int prob = idx >> 11;
        const int rem  = idx & 2047;
        const int r    = rem >> 8;             // 0..7 -> row 8+r
        const int u    = rem & 255;
        const int c32  = u >> 2;
        const int g    = u & 3;
        const unsigned w = (r == 0) ? 0x3F803F80u : 0u;  // row 8 = ones (rowsum)
        V164[prob * 4096 + c32 * 64 + g * 16 + (8 + r)] = uint4{w, w, w, w};
    }
}

// ---------------- main: one 4-wave block per 64-row strip ----------------
// Per 32-key chunk: QK transposed d = mfma(A=K, B=Q[f]) -> lane(g,li) reg r =
// P[key=32p+16t+4g+r][query=i0+16f+li]; exp2; pack = PV A-frag under key-order
// sigma (V staged in sigma order); PV = mfma(pa, V). One K/V load feeds 4
// Q-frags (12 MFMAs) -> 4x load amortization vs r10. V row 8 = ones gives the
// softmax denominator in acc col 8. Diagonal-crossing chunks (p >= 2*s64) use
// per-reg threshold masks. 4 waves stride chunks; additive partials merge in
// LDS; wave f normalizes+stores frag f.
__global__ __launch_bounds__(256) void attn_main(
    const float* __restrict__ Q, const uint4* __restrict__ Kt4,
    const uint4* __restrict__ V164, float* __restrict__ OUT)
{
    const int bid  = blockIdx.x;
    const int prob = bid % NPROB;
    const int s64  = (NSTRIP64 - 1) - (bid / NPROB);  // longest strips first
    const int i0   = s64 * 64;
    const int t  = threadIdx.x;
    const int w  = t >> 6;                  // wave 0..3
    const int l  = t & 63;                  // lane
    const int li = l & 15, g = l >> 4;

    const uint4* Ktp = Kt4 + prob * SEQ;
    const uint4* Vp  = V164 + prob * 4096;  // [64 chunks][64] uint4

    // In-kernel Q pack: frag f = queries i0+16f+li (g==0 lanes only; padded
    // k-slots of the K A-frag must multiply by zero).
    const float* Qp = Q + prob * CK * SEQ;
    union { bf16x8 v; uint4 u; } qf[4];
#pragma unroll
    for (int f = 0; f < 4; ++f) {
        uint4 qo = {0u, 0u, 0u, 0u};
        if (g == 0) {
            const int qi = i0 + 16 * f + li;
            qo.x = packbf(Qp[0 * SEQ + qi] * QSCALE, Qp[1 * SEQ + qi] * QSCALE);
            qo.y = packbf(Qp[2 * SEQ + qi] * QSCALE, Qp[3 * SEQ + qi] * QSCALE);
            qo.z = packbf(Qp[4 * SEQ + qi] * QSCALE, Qp[5 * SEQ + qi] * QSCALE);
            qo.w = packbf(Qp[6 * SEQ + qi] * QSCALE, Qp[7 * SEQ + qi] * QSCALE);
        }
        qf[f].u = qo;
    }

    f32x4 acc[4];
#pragma unroll
    for (int f = 0; f < 4; ++f) acc[f] = f32x4{0.f, 0.f, 0.f, 0.f};
    const f32x4 zc = {0.f, 0.f, 0.f, 0.f};

    const int pint = 2 * s64;               // chunks >= pint cross the diagonal
    const int pmax = 2 * s64 + 1;           // last chunk

    for (int p = w; p <= pmax; p += 4) {
        union { bf16x8 v; uint4 u; } k0, k1, vf;
        k0.u = Ktp[p * 32 + li];            // keys 32p..+15 (broadcast x4)
        k1.u = Ktp[p * 32 + 16 + li];       // keys 32p+16..+31
        vf.u = Vp[(p << 6) + l];            // sigma-interleaved V, coalesced
        if (p < pint) {                     // interior: unmasked
#pragma unroll
            for (int f = 0; f < 4; ++f) {
                f32x4 d0 = __builtin_amdgcn_mfma_f32_16x16x32_bf16(k0.v, qf[f].v, zc, 0, 0, 0);
                f32x4 d1 = __builtin_amdgcn_mfma_f32_16x16x32_bf16(k1.v, qf[f].v, zc, 0, 0, 0);
#pragma unroll
                for (int r = 0; r < 4; ++r) { d0[r] = exp2f(d0[r]); d1[r] = exp2f(d1[r]); }
                union { bf16x8 v; unsigned u[4]; } pa;
                pa.u[0] = packbf(d0[0], d0[1]);
                pa.u[1] = packbf(d0[2], d0[3]);
                pa.u[2] = packbf(d1[0], d1[1]);
                pa.u[3] = packbf(d1[2], d1[3]);
                acc[f] = __builtin_amdgcn_mfma_f32_16x16x32_bf16(pa.v, vf.v, acc[f], 0, 0, 0);
            }
        } else {                            // diagonal-crossing: per-reg threshold
#pragma unroll
            for (int f = 0; f < 4; ++f) {
                const int thr0 = i0 + 16 * f + li - 32 * p - 4 * g;  // keep r <= thr
                const int thr1 = thr0 - 16;
                f32x4 d0 = __builtin_amdgcn_mfma_f32_16x16x32_bf16(k0.v, qf[f].v, zc, 0, 0, 0);
                f32x4 d1 = __builtin_amdgcn_mfma_f32_16x16x32_bf16(k1.v, qf[f].v, zc, 0, 0, 0);
#pragma unroll
                for (int r = 0; r < 4; ++r) {
                    d0[r] = (r <= thr0) ? exp2f(d0[r]) : 0.f;
                    d1[r] = (r <= thr1) ? exp2f(d1[r]) : 0.f;
                }
                union { bf16x8 v; unsigned u[4]; } pa;
                pa.u[0] = packbf(d0[0], d0[1]);
                pa.u[1] = packbf(d0[2], d0[3]);
                pa.u[2] = packbf(d1[0], d1[1]);
                pa.u[3] = packbf(d1[2], d1[3]);
                acc[f] = __builtin_amdgcn_mfma_f32_16x16x32_bf16(pa.v, vf.v, acc[f], 0, 0, 0);
            }
        }
    }

    // merge additive partials: lds[wave][frag][lane]; wave f finishes frag f
    __shared__ f32x4 lds[4][4][64];         // 16 KB
#pragma unroll
    for (int f = 0; f < 4; ++f) lds[w][f][l] = acc[f];
    __syncthreads();

    f32x4 a = lds[0][w][l];
#pragma unroll
    for (int ww = 1; ww < 4; ++ww) {
        const f32x4 o = lds[ww][w][l];
#pragma unroll
        for (int r = 0; r < 4; ++r) a[r] += o[r];
    }

    // a = D[row=query 4g+r][col=li]; col 8 = rowsum (ones row of V).
    // rowsum for this frag's query 4g+r lives at lane 16g+8, reg r.
    const int idxR = ((g << 4) + 8) << 2;
    float inv[4];
#pragma unroll
    for (int r = 0; r < 4; ++r) {
        const float rs = __int_as_float(
            __builtin_amdgcn_ds_bpermute(idxR, __float_as_int(a[r])));
        inv[r] = 1.0f / rs;
    }
    if (li < CK) {
#pragma unroll
        for (int r = 0; r < 4; ++r)
            OUT[(prob * CK + li) * SEQ + i0 + 16 * w + 4 * g + r] = a[r] * inv[r];
    }
}

extern "C" void kernel_launch(void* const* d_in, const int* in_sizes, int n_in,
                              void* d_out, int out_size, void* d_ws, size_t ws_size,
                              hipStream_t stream) {
    // setup_inputs order: keys, queries, values, attn_mask (=tril, folded), num_heads (=8)
    const float* K = (const float*)d_in[0];
    const float* Q = (const float*)d_in[1];
    const float* V = (const float*)d_in[2];
    float* OUT = (float*)d_out;

    // ws layout (bytes): Kt[0, 786432) V16[786432, 2359296)
    uint4* Kt4  = (uint4*)d_ws;
    uint4* V164 = (uint4*)((char*)d_ws + 786432);

    prepass<<<dim3((TK + TB + TC) / 256), dim3(256), 0, stream>>>(K, V, Kt4, V164);
    attn_main<<<dim3(NPROB * NSTRIP64), dim3(256), 0, stream>>>(Q, Kt4, V164, OUT);
}